// Round 4
// baseline (365.489 us; speedup 1.0000x reference)
//
#include <hip/hip_runtime.h>
#include <math.h>

#ifndef __has_builtin
#define __has_builtin(x) 0
#endif

#define S_LEN 2048
#define B_N   4096

__device__ __forceinline__ float hw_exp2(float x) { return __builtin_amdgcn_exp2f(x); }
__device__ __forceinline__ float hw_rcp(float x)  { return __builtin_amdgcn_rcpf(x); }

// DPP ctrls (all within a 16-lane row unless noted):
//   0x55*K : quad_perm broadcast lane K of each quad
//   0x1B   : quad_perm [3,2,1,0]  == lane ^ 3
//   0x128  : row_ror:8            == lane ^ 8
//   0x141  : row_half_mirror      == lane ^ 7
//   0x142  : row_bcast15          == lane15 -> lanes16..31 (lane47 -> 48..63)
template<int CTRL>
__device__ __forceinline__ float dpp_mov(float v) {
    return __int_as_float(__builtin_amdgcn_mov_dpp(__float_as_int(v), CTRL, 0xF, 0xF, false));
}
// cross-row broadcast; rows with no valid source read 0 (old=0, bound_ctrl=1)
__device__ __forceinline__ float dpp_bcast15(float v) {
    return __int_as_float(__builtin_amdgcn_update_dpp(0, __float_as_int(v), 0x142, 0xF, 0xF, true));
}
template<int K>
__device__ __forceinline__ float quad_bcast(float v) { return dpp_mov<K * 0x55>(v); }

// tanh(c) = 1 - 2/(1 + exp(2c)), overflow-safe
__device__ __forceinline__ float tanh_c(float c) {
    const float TWO_LOG2E = 2.8853900817779268f;
    float e = hw_exp2(c * TWO_LOG2E);
    float r = hw_rcp(1.0f + e);
    return fmaf(-2.0f, r, 1.0f);
}

__global__ __launch_bounds__(256) void lstm2_kernel(
    const float* __restrict__ X,
    const float* __restrict__ Wih0, const float* __restrict__ Whh0,
    const float* __restrict__ bih0, const float* __restrict__ bhh0,
    const float* __restrict__ Wih1, const float* __restrict__ Whh1,
    const float* __restrict__ bih1, const float* __restrict__ bhh1,
    const float* __restrict__ Wout, const float* __restrict__ bOut,
    float* __restrict__ Y)
{
    const int tid  = blockIdx.x * blockDim.x + threadIdx.x;
    const int b    = tid >> 5;          // chain: 32 lanes each
    const int half = (tid >> 4) & 1;    // 0 = layer0 lanes, 1 = layer1 lanes
    const int l16  = tid & 15;
    const int m    = l16 >> 2;          // hidden unit (quad index)
    const int g    = l16 & 3;           // gate: 0=i 1=f 2=g 3=o
    const int j    = g * 4 + m;         // row in the (4H) stacked weight layout

    const float LOG2E = 1.4426950408889634f;
    const bool  is_tanh = (g == 2);
    const float s  = is_tanh ? (2.0f * LOG2E) : (-LOG2E);
    const float ka = is_tanh ? -2.0f : 1.0f;
    const float kb = is_tanh ?  1.0f : 0.0f;

    // Uniform gate: z = sum_d P[d]*u[d] + sum_d Q[d]*v[d] + bias
    //  L0 lanes: u = (x, n1, n2, n3) with P = (a0,0,0,0); v = h1v, Q = U0
    //  L1 lanes: u = n (h1 handoff, n[e] = h1[3^e]);       v = h2v, Q = U1
    float P[4], Q[4], bias;
    if (half == 0) {
        P[0] = Wih0[j] * s; P[1] = 0.f; P[2] = 0.f; P[3] = 0.f;
        #pragma unroll
        for (int d = 0; d < 4; ++d) Q[d] = Whh0[j * 4 + (m ^ d)] * s;
        bias = (bih0[j] + bhh0[j]) * s;
    } else {
        #pragma unroll
        for (int e = 0; e < 4; ++e) P[e] = Wih1[j * 4 + (3 ^ e)] * s;
        #pragma unroll
        for (int d = 0; d < 4; ++d) Q[d] = Whh1[j * 4 + (m ^ d)] * s;
        bias = (bih1[j] + bhh1[j]) * s;
    }
    float wop[4];
    #pragma unroll
    for (int d = 0; d < 4; ++d) wop[d] = Wout[m ^ d];
    const float bo = bOut[0];

    // per-lane state: own broadcast h vector v[d] (= h[m^d]) and cell c;
    // n = incoming handoff (h1 for L1 lanes), 0-init
    float c = 0.f;
    float v0 = 0.f, v1 = 0.f, v2 = 0.f, v3 = 0.f;
    float n0 = 0.f, n1 = 0.f, n2 = 0.f, n3 = 0.f;

    const float* xp = X + b;
    float*       yp = Y + b;
    const bool is_store = ((tid & 31) == 16);   // first L1 lane (m'=0)

    float xbuf[8];
    #pragma unroll
    for (int u = 0; u < 8; ++u) xbuf[u] = xp[u * B_N];
    float ybuf[8];

    // One fused step: L0 lanes do layer0 step i, L1 lanes do layer1 step i-1.
    auto sub = [&](float x, float& yout) {
        float u0 = half ? n0 : x;
        float zp = fmaf(P[0], u0, bias);
        zp = fmaf(P[1], n1, zp);
        float zq = fmaf(P[3], n3, P[2] * n2);
        float za = fmaf(Q[1], v1, Q[0] * v0);
        float zb = fmaf(Q[3], v3, Q[2] * v2);
        float z  = (zp + zq) + (za + zb);
        float r  = hw_rcp(1.0f + hw_exp2(z));
        float act = fmaf(ka, r, kb);
        float iv = quad_bcast<0>(act), fv = quad_bcast<1>(act);
        float gv = quad_bcast<2>(act), ov = quad_bcast<3>(act);
        c = fmaf(fv, c, iv * gv);
        float h = ov * tanh_c(c);
        v0 = h;
        v1 = dpp_mov<0x1B>(dpp_mov<0x141>(h)); // xor4
        v2 = dpp_mov<0x128>(h);                // xor8
        v3 = dpp_mov<0x128>(v1);               // xor12
        // handoff h1(i) -> L1 lanes for next iteration (L0 rows get 0)
        n0 = dpp_bcast15(v0);
        n1 = dpp_bcast15(v1);
        n2 = dpp_bcast15(v2);
        n3 = dpp_bcast15(v3);
        // output projection (meaningful on L1 lanes: v = h2v)
        float y = fmaf(wop[0], v0, bo);
        y = fmaf(wop[1], v1, y);
        y = fmaf(wop[2], v2, y);
        y = fmaf(wop[3], v3, y);
        yout = y;
    };

    // ---- first block (iterations 0..7) ----
    {
        #pragma unroll
        for (int u = 0; u < 8; ++u) {
            float x = xbuf[u];
            xbuf[u] = xp[(u + 8) * B_N];
            sub(x, ybuf[u]);
            if (u == 0 && half) {        // discard L1's bogus step "-1"
                c = 0.f; v0 = 0.f; v1 = 0.f; v2 = 0.f; v3 = 0.f;
            }
        }
        if (is_store) {
            #pragma unroll
            for (int u = 1; u < 8; ++u) yp[(u - 1) * B_N] = ybuf[u];
        }
    }

    // ---- main blocks (iterations 8..2047; L1 covers steps 7..2046) ----
    for (int t0 = 8; t0 < S_LEN; t0 += 8) {
        #pragma unroll
        for (int u = 0; u < 8; ++u) {
            const int t = t0 + u;
            float x = xbuf[u];
            int tn = t + 8; if (tn > S_LEN - 1) tn = S_LEN - 1;
            xbuf[u] = xp[tn * B_N];
            sub(x, ybuf[u]);
        }
        if (is_store) {
            #pragma unroll
            for (int u = 0; u < 8; ++u) yp[(t0 - 1 + u) * B_N] = ybuf[u];
        }
    }

    // ---- epilogue: one more iteration so L1 finishes step 2047 ----
    {
        float yfin;
        sub(xbuf[0], yfin);              // L0 does a harmless extra step
        if (is_store) yp[(S_LEN - 1) * B_N] = yfin;
    }
}

extern "C" void kernel_launch(void* const* d_in, const int* in_sizes, int n_in,
                              void* d_out, int out_size, void* d_ws, size_t ws_size,
                              hipStream_t stream) {
    const float* X    = (const float*)d_in[0];
    const float* Wih0 = (const float*)d_in[1];
    const float* Whh0 = (const float*)d_in[2];
    const float* bih0 = (const float*)d_in[3];
    const float* bhh0 = (const float*)d_in[4];
    const float* Wih1 = (const float*)d_in[5];
    const float* Whh1 = (const float*)d_in[6];
    const float* bih1 = (const float*)d_in[7];
    const float* bhh1 = (const float*)d_in[8];
    const float* Wout = (const float*)d_in[9];
    const float* bOut = (const float*)d_in[10];
    float* Y = (float*)d_out;

    // 4096 chains x 32 lanes = 131072 threads = 2048 waves = 2 waves/SIMD
    dim3 grid(512), block(256);
    hipLaunchKernelGGL(lstm2_kernel, grid, block, 0, stream,
                       X, Wih0, Whh0, bih0, bhh0, Wih1, Whh1, bih1, bhh1, Wout, bOut, Y);
}

// Round 5
// 312.902 us; speedup vs baseline: 1.1681x; 1.1681x over previous
//
#include <hip/hip_runtime.h>
#include <math.h>

#define S_LEN 2048
#define B_N   4096
#define CPB   8            // chains per block
#define NBLK  (S_LEN / 8)  // 256 eight-step blocks

__device__ __forceinline__ float hw_exp2(float x) { return __builtin_amdgcn_exp2f(x); }
__device__ __forceinline__ float hw_rcp(float x)  { return __builtin_amdgcn_rcpf(x); }

// DPP ctrls (within 16-lane rows; all involutions, no direction ambiguity):
//   0x55*K : quad_perm broadcast lane K of each quad
//   0x1B   : quad_perm [3,2,1,0]  == lane ^ 3
//   0x128  : row_ror:8            == lane ^ 8
//   0x141  : row_half_mirror      == lane ^ 7
template<int CTRL>
__device__ __forceinline__ float dpp_mov(float v) {
    return __int_as_float(__builtin_amdgcn_mov_dpp(__float_as_int(v), CTRL, 0xF, 0xF, false));
}
template<int K>
__device__ __forceinline__ float quad_bcast(float v) { return dpp_mov<K * 0x55>(v); }

// tanh(c) = 1 - 2/(1 + exp(2c)), overflow-safe
__device__ __forceinline__ float tanh_c(float c) {
    const float TWO_LOG2E = 2.8853900817779268f;
    float e = hw_exp2(c * TWO_LOG2E);
    float r = hw_rcp(1.0f + e);
    return fmaf(-2.0f, r, 1.0f);
}

__global__ __launch_bounds__(256) void lstm2_kernel(
    const float* __restrict__ X,
    const float* __restrict__ Wih0, const float* __restrict__ Whh0,
    const float* __restrict__ bih0, const float* __restrict__ bhh0,
    const float* __restrict__ Wih1, const float* __restrict__ Whh1,
    const float* __restrict__ bih1, const float* __restrict__ bhh1,
    const float* __restrict__ Wout, const float* __restrict__ bOut,
    float* __restrict__ Y)
{
    const int tix  = threadIdx.x;
    const int role = tix >> 7;            // 0 = layer0 waves (0,1), 1 = layer1 waves (2,3)
    const int cpos = (tix & 127) >> 4;    // chain slot within block (0..7)
    const int l16  = tix & 15;
    const int m    = l16 >> 2;            // hidden unit (quad index)
    const int g    = l16 & 3;             // gate: 0=i 1=f 2=g 3=o
    const int j    = g * 4 + m;           // row in the (4H) stacked weight layout
    const int b    = blockIdx.x * CPB + cpos;

    // h1 handoff ring: [buf][chain][step][unit]
    __shared__ float ring[2][CPB][8][4];

    const float LOG2E = 1.4426950408889634f;
    const bool  is_tanh = (g == 2);
    // sigmoid rows: z = -log2e*pre;  sigmoid = rcp(1+exp2(z))
    // tanh rows:    z = +2log2e*pre; tanh    = 1 - 2*rcp(1+exp2(z))
    const float s  = is_tanh ? (2.0f * LOG2E) : (-LOG2E);
    const float ka = is_tanh ? -2.0f : 1.0f;
    const float kb = is_tanh ?  1.0f : 0.0f;

    // role-specific weights (prescaled)
    float a0 = 0.f, bias = 0.f, U[4], Wi[4], wop[4], bo = 0.f;
    if (role == 0) {
        a0   = Wih0[j] * s;
        bias = (bih0[j] + bhh0[j]) * s;
        #pragma unroll
        for (int d = 0; d < 4; ++d) U[d] = Whh0[j * 4 + (m ^ d)] * s;
        #pragma unroll
        for (int d = 0; d < 4; ++d) { Wi[d] = 0.f; wop[d] = 0.f; }
    } else {
        bias = (bih1[j] + bhh1[j]) * s;
        #pragma unroll
        for (int e = 0; e < 4; ++e) Wi[e] = Wih1[j * 4 + e] * s;   // canonical order
        #pragma unroll
        for (int d = 0; d < 4; ++d) U[d] = Whh1[j * 4 + (m ^ d)] * s;
        #pragma unroll
        for (int d = 0; d < 4; ++d) wop[d] = Wout[m ^ d];
        bo = bOut[0];
    }

    // per-lane recurrent state for this wave's layer:
    // v[d] = h[m^d] broadcast vector, c = own unit's cell
    float c = 0.f, v0 = 0.f, v1 = 0.f, v2 = 0.f, v3 = 0.f;

    // gate tail: z -> activation -> gate gather -> c update -> h -> h spread
    auto gate_tail = [&](float z) {
        float r   = hw_rcp(1.0f + hw_exp2(z));
        float act = fmaf(ka, r, kb);
        float iv = quad_bcast<0>(act), fv = quad_bcast<1>(act);
        float gv = quad_bcast<2>(act), ov = quad_bcast<3>(act);
        c = fmaf(fv, c, iv * gv);
        float h = ov * tanh_c(c);
        v0 = h;
        v1 = dpp_mov<0x1B>(dpp_mov<0x141>(h)); // xor4
        v2 = dpp_mov<0x128>(h);                // xor8
        v3 = dpp_mov<0x128>(v1);               // xor12
    };

    float xbuf[8];
    if (role == 0) {
        #pragma unroll
        for (int u = 0; u < 8; ++u) xbuf[u] = X[u * B_N + b];
    }
    float ybuf[8];

    // Skewed pipeline: iteration kk -> L0 computes steps [8kk, 8kk+8) into
    // ring[kk&1]; L1 computes steps [8(kk-1), 8kk) from ring[(kk-1)&1].
    for (int kk = 0; kk <= NBLK; ++kk) {
        if (role == 0) {
            if (kk < NBLK) {
                const int t0 = kk * 8;
                float* wr = &ring[kk & 1][cpos][0][0];
                #pragma unroll
                for (int u = 0; u < 8; ++u) {
                    float x = xbuf[u];
                    int tn = t0 + 8 + u; if (tn > S_LEN - 1) tn = S_LEN - 1;
                    xbuf[u] = X[tn * B_N + b];          // prefetch next block
                    float z = fmaf(x, a0, bias);
                    z = fmaf(U[0], v0, z);
                    z = fmaf(U[1], v1, z);
                    z = fmaf(U[2], v2, z);
                    z = fmaf(U[3], v3, z);
                    gate_tail(z);
                    if (g == 0) wr[u * 4 + m] = v0;     // h1[m], one lane per unit
                }
            }
        } else {
            if (kk >= 1) {
                const int t0 = (kk - 1) * 8;
                const float4* rd = (const float4*)&ring[(kk - 1) & 1][cpos][0][0];
                float4 n[8];
                #pragma unroll
                for (int u = 0; u < 8; ++u) n[u] = rd[u];   // broadcast b128 reads
                #pragma unroll
                for (int u = 0; u < 8; ++u) {
                    float z = fmaf(Wi[0], n[u].x, bias);
                    z = fmaf(Wi[1], n[u].y, z);
                    z = fmaf(Wi[2], n[u].z, z);
                    z = fmaf(Wi[3], n[u].w, z);
                    z = fmaf(U[0], v0, z);
                    z = fmaf(U[1], v1, z);
                    z = fmaf(U[2], v2, z);
                    z = fmaf(U[3], v3, z);
                    gate_tail(z);
                    float y = fmaf(wop[0], v0, bo);
                    y = fmaf(wop[1], v1, y);
                    y = fmaf(wop[2], v2, y);
                    y = fmaf(wop[3], v3, y);
                    ybuf[u] = y;
                }
                if (l16 == 0) {
                    #pragma unroll
                    for (int u = 0; u < 8; ++u) Y[(t0 + u) * B_N + b] = ybuf[u];
                }
            }
        }
        __syncthreads();
    }
}

extern "C" void kernel_launch(void* const* d_in, const int* in_sizes, int n_in,
                              void* d_out, int out_size, void* d_ws, size_t ws_size,
                              hipStream_t stream) {
    const float* X    = (const float*)d_in[0];
    const float* Wih0 = (const float*)d_in[1];
    const float* Whh0 = (const float*)d_in[2];
    const float* bih0 = (const float*)d_in[3];
    const float* bhh0 = (const float*)d_in[4];
    const float* Wih1 = (const float*)d_in[5];
    const float* Whh1 = (const float*)d_in[6];
    const float* bih1 = (const float*)d_in[7];
    const float* bhh1 = (const float*)d_in[8];
    const float* Wout = (const float*)d_in[9];
    const float* bOut = (const float*)d_in[10];
    float* Y = (float*)d_out;

    // 512 blocks x 256 threads: 8 chains/block, waves 0-1 = layer0, waves 2-3
    // = layer1. 2048 waves total = 2 waves/SIMD; 2 blocks/CU.
    dim3 grid(B_N / CPB), block(256);
    hipLaunchKernelGGL(lstm2_kernel, grid, block, 0, stream,
                       X, Wih0, Whh0, bih0, bhh0, Wih1, Whh1, bih1, bhh1, Wout, bOut, Y);
}